// Round 4
// baseline (1257.666 us; speedup 1.0000x reference)
//
#include <hip/hip_runtime.h>

#define B 4
#define CIN 256
#define T 8192
#define NL 24
#define TP (64 + T + 8)      // 64 zero halo rows + T + overshoot
#define SQRT_HALF 0.70710678118654752f
#define SKIP_SCALE 0.20412414523193150f  // (1/24)^0.5

typedef unsigned short u16;
typedef __attribute__((ext_vector_type(4))) float f32x4;
typedef __attribute__((ext_vector_type(8))) short s16x8;
typedef __attribute__((ext_vector_type(4))) short s16x4;

__device__ inline u16 f2bf(float f) {            // RNE float->bf16
  unsigned u = __float_as_uint(f);
  return (u16)((u + 0x7fffu + ((u >> 16) & 1u)) >> 16);
}
__device__ inline void gload_lds16(const void* g, void* l) {
  __builtin_amdgcn_global_load_lds(
      (const __attribute__((address_space(1))) unsigned*)g,
      (__attribute__((address_space(3))) unsigned*)l, 16, 0, 0);
}
__device__ inline float gate_fn(float a, float g) {
  float e2 = __expf(-2.f * fabsf(a));
  float th = (1.f - e2) * __builtin_amdgcn_rcpf(1.f + e2);
  float sg = __builtin_amdgcn_rcpf(1.f + __expf(-g));
  return copysignf(th, a) * sg;
}

// ---------------- weight prep ----------------
__global__ void cvt_convw(const float* __restrict__ src, u16* __restrict__ dst) {
  int i = blockIdx.x * 256 + threadIdx.x;          // N = 24*3*256*128
  if (i >= NL * 3 * 256 * 128) return;
  int c = i & 127, o = (i >> 7) & 255, kk = (i >> 15) % 3, l = (i >> 15) / 3;
  dst[i] = f2bf(src[(((size_t)l * 256 + o) * 128 + c) * 3 + kk]);
}
__global__ void cvt_sow(const float* __restrict__ skw, const float* __restrict__ otw,
                        u16* __restrict__ dst) {
  int i = blockIdx.x * 256 + threadIdx.x;          // N = 24*256*128
  if (i >= NL * 256 * 128) return;
  int c = i & 127, r = (i >> 7) & 255, l = i >> 15;
  float v = (r < 128) ? skw[((size_t)l * 128 + r) * 128 + c]
                      : otw[((size_t)l * 128 + (r - 128)) * 128 + c];
  dst[i] = f2bf(v);
}
__global__ void cvt_plain(const float* __restrict__ s, u16* __restrict__ d, int n) {
  int i = blockIdx.x * 256 + threadIdx.x;
  if (i < n) d[i] = f2bf(s[i]);
}
__global__ void padzero(u16* __restrict__ hb) {
  int i = blockIdx.x * 256 + threadIdx.x;          // N = 4*64*128
  if (i >= B * 64 * 128) return;
  int c = i & 127, r = (i >> 7) & 63, b = i >> 13;
  hb[((size_t)b * TP + r) * 128 + c] = 0;
}
__global__ void sumsb_kernel(const float* __restrict__ sb, float* __restrict__ dst) {
  int c = threadIdx.x;                             // 128
  float s = 0.f;
  for (int l = 0; l < NL; l++) s += sb[l * 128 + c];
  dst[c] = s;
}
__global__ void zeroflags(int* __restrict__ f, int n) {
  int i = blockIdx.x * 256 + threadIdx.x;
  if (i < n) f[i] = 0;
}

// ---------------- persistent fused WaveNet ----------------
// 512 blocks x 512 threads; block = (b, 64-t tile). Co-residency guaranteed:
// launch_bounds(512,4) caps VGPR at 128, LDS 48KB -> 2 blocks/CU x 256 CUs.
// Sync: halo-wait on bid-1 (flg), overwrite back-pressure on bid+1 (ack).
__global__ __launch_bounds__(512, 4)
void wavenet_kernel(const float* __restrict__ x,
                    const u16* __restrict__ wf, const float* __restrict__ fb,
                    const u16* __restrict__ wcv, const float* __restrict__ cbv,
                    const u16* __restrict__ wso, const float* __restrict__ obv,
                    const u16* __restrict__ w1, const float* __restrict__ b1,
                    const u16* __restrict__ w2, const float* __restrict__ b2,
                    const float* __restrict__ sumsb,
                    u16* __restrict__ hG0, u16* __restrict__ hG1,
                    int* __restrict__ flg, int* __restrict__ ack,
                    float* __restrict__ out)
{
  __shared__ u16 h_s[128 * 128];  // 32KB: conv input rows (halo+own), 256B rows
  __shared__ u16 zh[64 * 128];    // 16KB: z tile / h out-staging, 256B rows
  const int tid = threadIdx.x, wv = tid >> 6, lane = tid & 63, lo = lane & 15, hi = lane >> 4;
  const int bid = blockIdx.x, tj = bid & 127, b = bid >> 7, t0 = tj * 64;

  f32x4 res[2][4];   // waves 0-3: skip accum; waves 4-7: hf residual (fp32)
  f32x4 acc[2][4];
  #pragma unroll
  for (int m = 0; m < 2; m++)
    #pragma unroll
    for (int n = 0; n < 4; n++) res[m][n] = (f32x4){0.f, 0.f, 0.f, 0.f};

  // ===== first conv: h = first_w @ x + first_b =====
  // stage x tile transposed->bf16 into h_s viewed as 64 rows x 512B (swizzled)
  #pragma unroll
  for (int it = 0; it < 8; it++) {
    int idx = tid + it * 512;                      // 4096 f32x4
    int c = idx >> 4, t4 = (idx & 15) << 2;
    f32x4 v = *(const f32x4*)(x + ((size_t)b * CIN + c) * T + t0 + t4);
    #pragma unroll
    for (int j = 0; j < 4; j++) {
      int t = t4 + j;
      *(u16*)((char*)h_s + t * 512 + ((c * 2) ^ ((t & 7) << 4))) = f2bf(v[j]);
    }
  }
  __syncthreads();
  if (wv >= 4) {
    #pragma unroll
    for (int m = 0; m < 2; m++)
      #pragma unroll
      for (int n = 0; n < 4; n++) acc[m][n] = (f32x4){0.f, 0.f, 0.f, 0.f};
    #pragma unroll
    for (int s = 0; s < 8; s++) {
      s16x8 af0 = *(const s16x8*)(wf + (size_t)((wv - 4) * 32 + lo) * CIN + s * 32 + hi * 8);
      s16x8 af1 = *(const s16x8*)(wf + (size_t)((wv - 4) * 32 + 16 + lo) * CIN + s * 32 + hi * 8);
      s16x8 bf[4];
      #pragma unroll
      for (int n = 0; n < 4; n++) {
        int t = n * 16 + lo;
        bf[n] = *(const s16x8*)((const char*)h_s + t * 512 + ((s * 64 + hi * 16) ^ ((t & 7) << 4)));
      }
      #pragma unroll
      for (int n = 0; n < 4; n++) {
        acc[0][n] = __builtin_amdgcn_mfma_f32_16x16x32_bf16(af0, bf[n], acc[0][n], 0, 0, 0);
        acc[1][n] = __builtin_amdgcn_mfma_f32_16x16x32_bf16(af1, bf[n], acc[1][n], 0, 0, 0);
      }
    }
    #pragma unroll
    for (int m = 0; m < 2; m++) {
      f32x4 fb4 = *(const f32x4*)(fb + (wv - 4) * 32 + m * 16 + hi * 4);
      #pragma unroll
      for (int n = 0; n < 4; n++) res[m][n] = acc[m][n] + fb4;
    }
    // pack h -> zh (bf16, swizzled)
    #pragma unroll
    for (int m = 0; m < 2; m++) {
      int c0 = (wv - 4) * 32 + m * 16 + hi * 4;
      #pragma unroll
      for (int n = 0; n < 4; n++) {
        int tl = n * 16 + lo;
        s16x4 pk;
        #pragma unroll
        for (int j = 0; j < 4; j++) pk[j] = (short)f2bf(res[m][n][j]);
        *(s16x4*)((char*)zh + tl * 256 + ((c0 * 2) ^ ((tl & 7) << 4))) = pk;
      }
    }
  }
  __syncthreads();
  {
    u16* gd = hG0 + ((size_t)b * TP + 64 + t0) * 128;
    #pragma unroll
    for (int i = 0; i < 2; i++)
      *(s16x8*)((char*)gd + (tid + i * 512) * 16) = *(const s16x8*)((const char*)zh + (tid + i * 512) * 16);
  }
  __syncthreads();
  if (tid == 0)
    __hip_atomic_store(flg + bid * 32, 1, __ATOMIC_RELEASE, __HIP_MEMORY_SCOPE_AGENT);

  // ===== 24 layers =====
  #pragma unroll 1
  for (int i = 0; i < NL; i++) {
    const int d = 1 << (i % 6);
    const u16* hGin = (i & 1) ? hG1 : hG0;
    const u16* wc = wcv + (size_t)i * 3 * 256 * 128;
    const float* cb = cbv + i * 256;
    const u16* wsl = wso + (size_t)i * 256 * 128;
    const float* ob = obv + i * 128;

    // phase A: hw waves pack own h rows into h_s at row offset 2d; tid0 spins for halo
    if (wv >= 4) {
      #pragma unroll
      for (int m = 0; m < 2; m++) {
        int c0 = (wv - 4) * 32 + m * 16 + hi * 4;
        #pragma unroll
        for (int n = 0; n < 4; n++) {
          int tl = n * 16 + lo;
          s16x4 pk;
          #pragma unroll
          for (int j = 0; j < 4; j++) pk[j] = (short)f2bf(res[m][n][j]);
          *(s16x4*)((char*)h_s + (2 * d + tl) * 256 + ((c0 * 2) ^ ((tl & 7) << 4))) = pk;
        }
      }
    } else if (tid == 0 && tj > 0) {
      while (__hip_atomic_load(flg + (bid - 1) * 32, __ATOMIC_ACQUIRE, __HIP_MEMORY_SCOPE_AGENT) < i + 1)
        __builtin_amdgcn_s_sleep(1);
    }
    __syncthreads();
    // phase B: halo rows 0..2d-1 from left neighbor (or zero pad) via global
    if (wv < 4) {
      const char* src = (const char*)(hGin + ((size_t)b * TP + 64 + t0 - 2 * d) * 128);
      int q = wv * 64 + lane;
      for (int p = q; p < 32 * d; p += 256)
        gload_lds16(src + p * 16, (char*)h_s + p * 16);
    }
    __syncthreads();
    if (tid == 0)
      __hip_atomic_store(ack + bid * 32, i + 1, __ATOMIC_RELEASE, __HIP_MEMORY_SCOPE_AGENT);

    // conv GEMM: wave owns a-rows [wv*16,+16) and g-rows [128+wv*16,+16)
    #pragma unroll
    for (int m = 0; m < 2; m++)
      #pragma unroll
      for (int n = 0; n < 4; n++) acc[m][n] = (f32x4){0.f, 0.f, 0.f, 0.f};
    const int oa = wv * 16, og = 128 + wv * 16;
    #pragma unroll
    for (int k = 0; k < 3; k++) {
      const int jb = k * d;
      const int st = ((lo + (k + 6) * d) & 7) << 4;
      #pragma unroll
      for (int s = 0; s < 4; s++) {
        s16x8 af0 = *(const s16x8*)(wc + ((size_t)(k * 256 + oa + lo)) * 128 + s * 32 + hi * 8);
        s16x8 af1 = *(const s16x8*)(wc + ((size_t)(k * 256 + og + lo)) * 128 + s * 32 + hi * 8);
        const int cbyte = s * 64 + hi * 16;
        s16x8 bf[4];
        #pragma unroll
        for (int n = 0; n < 4; n++) {
          int j = n * 16 + lo + jb;
          bf[n] = *(const s16x8*)((const char*)h_s + j * 256 + (cbyte ^ st));
        }
        #pragma unroll
        for (int n = 0; n < 4; n++) {
          acc[0][n] = __builtin_amdgcn_mfma_f32_16x16x32_bf16(af0, bf[n], acc[0][n], 0, 0, 0);
          acc[1][n] = __builtin_amdgcn_mfma_f32_16x16x32_bf16(af1, bf[n], acc[1][n], 0, 0, 0);
        }
      }
    }
    // gate -> zh
    {
      f32x4 ba = *(const f32x4*)(cb + oa + hi * 4);
      f32x4 bg = *(const f32x4*)(cb + og + hi * 4);
      #pragma unroll
      for (int n = 0; n < 4; n++) {
        int tl = n * 16 + lo;
        s16x4 pk;
        #pragma unroll
        for (int j = 0; j < 4; j++)
          pk[j] = (short)f2bf(gate_fn(acc[0][n][j] + ba[j], acc[1][n][j] + bg[j]));
        *(s16x4*)((char*)zh + tl * 256 + (((oa + hi * 4) * 2) ^ ((tl & 7) << 4))) = pk;
      }
    }
    __syncthreads();

    // skip/out GEMM (M=256 combined; rows [wv*32,+32))
    const int ro = wv * 32;
    if (wv < 4) {  // skip rows: accumulate directly into res via MFMA C-in
      #pragma unroll
      for (int s = 0; s < 4; s++) {
        s16x8 af0 = *(const s16x8*)(wsl + (size_t)(ro + lo) * 128 + s * 32 + hi * 8);
        s16x8 af1 = *(const s16x8*)(wsl + (size_t)(ro + 16 + lo) * 128 + s * 32 + hi * 8);
        const int cbyte = s * 64 + hi * 16;
        s16x8 bf[4];
        #pragma unroll
        for (int n = 0; n < 4; n++) {
          int tl = n * 16 + lo;
          bf[n] = *(const s16x8*)((const char*)zh + tl * 256 + (cbyte ^ ((tl & 7) << 4)));
        }
        #pragma unroll
        for (int n = 0; n < 4; n++) {
          res[0][n] = __builtin_amdgcn_mfma_f32_16x16x32_bf16(af0, bf[n], res[0][n], 0, 0, 0);
          res[1][n] = __builtin_amdgcn_mfma_f32_16x16x32_bf16(af1, bf[n], res[1][n], 0, 0, 0);
        }
      }
    } else {       // out rows: residual update into res
      #pragma unroll
      for (int m = 0; m < 2; m++)
        #pragma unroll
        for (int n = 0; n < 4; n++) acc[m][n] = (f32x4){0.f, 0.f, 0.f, 0.f};
      #pragma unroll
      for (int s = 0; s < 4; s++) {
        s16x8 af0 = *(const s16x8*)(wsl + (size_t)(ro + lo) * 128 + s * 32 + hi * 8);
        s16x8 af1 = *(const s16x8*)(wsl + (size_t)(ro + 16 + lo) * 128 + s * 32 + hi * 8);
        const int cbyte = s * 64 + hi * 16;
        s16x8 bf[4];
        #pragma unroll
        for (int n = 0; n < 4; n++) {
          int tl = n * 16 + lo;
          bf[n] = *(const s16x8*)((const char*)zh + tl * 256 + (cbyte ^ ((tl & 7) << 4)));
        }
        #pragma unroll
        for (int n = 0; n < 4; n++) {
          acc[0][n] = __builtin_amdgcn_mfma_f32_16x16x32_bf16(af0, bf[n], acc[0][n], 0, 0, 0);
          acc[1][n] = __builtin_amdgcn_mfma_f32_16x16x32_bf16(af1, bf[n], acc[1][n], 0, 0, 0);
        }
      }
      #pragma unroll
      for (int m = 0; m < 2; m++) {
        f32x4 ob4 = *(const f32x4*)(ob + (ro - 128) + m * 16 + hi * 4);
        #pragma unroll
        for (int n = 0; n < 4; n++)
          res[m][n] = (acc[m][n] + ob4 + res[m][n]) * SQRT_HALF;
      }
    }
    __syncthreads();   // zh reads done

    if (i < NL - 1) {
      // epilogue: pack new h -> zh; back-pressure; publish tile + flag
      if (wv >= 4) {
        #pragma unroll
        for (int m = 0; m < 2; m++) {
          int c0 = (wv - 4) * 32 + m * 16 + hi * 4;
          #pragma unroll
          for (int n = 0; n < 4; n++) {
            int tl = n * 16 + lo;
            s16x4 pk;
            #pragma unroll
            for (int j = 0; j < 4; j++) pk[j] = (short)f2bf(res[m][n][j]);
            *(s16x4*)((char*)zh + tl * 256 + ((c0 * 2) ^ ((tl & 7) << 4))) = pk;
          }
        }
      } else if (tid == 0 && tj < 127) {
        while (__hip_atomic_load(ack + (bid + 1) * 32, __ATOMIC_ACQUIRE, __HIP_MEMORY_SCOPE_AGENT) < i)
          __builtin_amdgcn_s_sleep(1);
      }
      __syncthreads();
      u16* gd = ((i & 1) ? hG0 : hG1) + ((size_t)b * TP + 64 + t0) * 128;
      #pragma unroll
      for (int q2 = 0; q2 < 2; q2++)
        *(s16x8*)((char*)gd + (tid + q2 * 512) * 16) = *(const s16x8*)((const char*)zh + (tid + q2 * 512) * 16);
      __syncthreads();
      if (tid == 0)
        __hip_atomic_store(flg + bid * 32, i + 2, __ATOMIC_RELEASE, __HIP_MEMORY_SCOPE_AGENT);
    }
  }

  // ===== heads =====
  // skip finalize: sT = relu((skip + sum_sb) * SKIP_SCALE) -> h_s (64 rows x 256B)
  if (wv < 4) {
    #pragma unroll
    for (int m = 0; m < 2; m++) {
      int c0 = wv * 32 + m * 16 + hi * 4;
      f32x4 sv = *(const f32x4*)(sumsb + c0);
      #pragma unroll
      for (int n = 0; n < 4; n++) {
        int tl = n * 16 + lo;
        s16x4 pk;
        #pragma unroll
        for (int j = 0; j < 4; j++)
          pk[j] = (short)f2bf(fmaxf((res[m][n][j] + sv[j]) * SKIP_SCALE, 0.f));
        *(s16x4*)((char*)h_s + tl * 256 + ((c0 * 2) ^ ((tl & 7) << 4))) = pk;
      }
    }
  }
  __syncthreads();
  // head1: s1 = relu(w1 @ sT + b1); wave owns 16 rows
  {
    f32x4 a1[4];
    #pragma unroll
    for (int n = 0; n < 4; n++) a1[n] = (f32x4){0.f, 0.f, 0.f, 0.f};
    #pragma unroll
    for (int s = 0; s < 4; s++) {
      s16x8 af = *(const s16x8*)(w1 + (size_t)(wv * 16 + lo) * 128 + s * 32 + hi * 8);
      #pragma unroll
      for (int n = 0; n < 4; n++) {
        int tl = n * 16 + lo;
        s16x8 bf = *(const s16x8*)((const char*)h_s + tl * 256 + ((s * 64 + hi * 16) ^ ((tl & 7) << 4)));
        a1[n] = __builtin_amdgcn_mfma_f32_16x16x32_bf16(af, bf, a1[n], 0, 0, 0);
      }
    }
    int c0 = wv * 16 + hi * 4;
    f32x4 b14 = *(const f32x4*)(b1 + c0);
    #pragma unroll
    for (int n = 0; n < 4; n++) {
      int tl = n * 16 + lo;
      s16x4 pk;
      #pragma unroll
      for (int j = 0; j < 4; j++) pk[j] = (short)f2bf(fmaxf(a1[n][j] + b14[j], 0.f));
      *(s16x4*)((char*)zh + tl * 256 + ((c0 * 2) ^ ((tl & 7) << 4))) = pk;
    }
  }
  __syncthreads();
  // head2: out = w2 @ s1 + b2; wave owns 32 rows; out [B][256][T]
  {
    const int ro = wv * 32;
    #pragma unroll
    for (int m = 0; m < 2; m++)
      #pragma unroll
      for (int n = 0; n < 4; n++) acc[m][n] = (f32x4){0.f, 0.f, 0.f, 0.f};
    #pragma unroll
    for (int s = 0; s < 4; s++) {
      s16x8 af0 = *(const s16x8*)(w2 + (size_t)(ro + lo) * 128 + s * 32 + hi * 8);
      s16x8 af1 = *(const s16x8*)(w2 + (size_t)(ro + 16 + lo) * 128 + s * 32 + hi * 8);
      #pragma unroll
      for (int n = 0; n < 4; n++) {
        int tl = n * 16 + lo;
        s16x8 bf = *(const s16x8*)((const char*)zh + tl * 256 + ((s * 64 + hi * 16) ^ ((tl & 7) << 4)));
        acc[0][n] = __builtin_amdgcn_mfma_f32_16x16x32_bf16(af0, bf, acc[0][n], 0, 0, 0);
        acc[1][n] = __builtin_amdgcn_mfma_f32_16x16x32_bf16(af1, bf, acc[1][n], 0, 0, 0);
      }
    }
    #pragma unroll
    for (int m = 0; m < 2; m++) {
      int c0 = ro + m * 16 + hi * 4;
      f32x4 b24 = *(const f32x4*)(b2 + c0);
      #pragma unroll
      for (int n = 0; n < 4; n++) {
        int t = t0 + n * 16 + lo;
        #pragma unroll
        for (int j = 0; j < 4; j++)
          out[((size_t)b * CIN + c0 + j) * T + t] = acc[m][n][j] + b24[j];
      }
    }
  }
}

// ---------------------------------------------------------------------------
extern "C" void kernel_launch(void* const* d_in, const int* in_sizes, int n_in,
                              void* d_out, int out_size, void* d_ws, size_t ws_size,
                              hipStream_t stream) {
  const float* x       = (const float*)d_in[0];
  const float* first_w = (const float*)d_in[1];
  const float* first_b = (const float*)d_in[2];
  const float* conv_w  = (const float*)d_in[3];
  const float* conv_b  = (const float*)d_in[4];
  const float* out_w   = (const float*)d_in[5];
  const float* out_b   = (const float*)d_in[6];
  const float* skip_w  = (const float*)d_in[7];
  const float* skip_b  = (const float*)d_in[8];
  const float* last1_w = (const float*)d_in[9];
  const float* last1_b = (const float*)d_in[10];
  const float* last2_w = (const float*)d_in[11];
  const float* last2_b = (const float*)d_in[12];
  float* out = (float*)d_out;

  u16* wsp = (u16*)d_ws;
  u16* wcv = wsp;                                   // 2,359,296
  u16* wsoB = wcv + (size_t)NL * 3 * 256 * 128;     // 786,432
  u16* wfB = wsoB + (size_t)NL * 256 * 128;         // 32,768
  u16* w1B = wfB + 128 * 256;                       // 16,384
  u16* w2B = w1B + 128 * 128;                       // 32,768
  float* sumsb = (float*)(w2B + 256 * 128);         // 128 f32
  u16* hG0 = (u16*)(sumsb + 128);
  u16* hG1 = hG0 + (size_t)B * TP * 128;
  int* flg = (int*)(hG1 + (size_t)B * TP * 128);    // 512*32 ints
  int* ack = flg + 512 * 32;

  cvt_convw<<<NL * 3 * 256 * 128 / 256, 256, 0, stream>>>(conv_w, wcv);
  cvt_sow<<<NL * 256 * 128 / 256, 256, 0, stream>>>(skip_w, out_w, wsoB);
  cvt_plain<<<128, 256, 0, stream>>>(first_w, wfB, 128 * 256);
  cvt_plain<<<64, 256, 0, stream>>>(last1_w, w1B, 128 * 128);
  cvt_plain<<<128, 256, 0, stream>>>(last2_w, w2B, 256 * 128);
  sumsb_kernel<<<1, 128, 0, stream>>>(skip_b, sumsb);
  padzero<<<128, 256, 0, stream>>>(hG0);
  padzero<<<128, 256, 0, stream>>>(hG1);
  zeroflags<<<128, 256, 0, stream>>>(flg, 512 * 32 * 2);

  wavenet_kernel<<<dim3(512), dim3(512), 0, stream>>>(
      x, wfB, first_b, wcv, conv_b, wsoB, out_b, w1B, last1_b, w2B, last2_b,
      sumsb, hG0, hG1, flg, ack, out);
}

// Round 7
// 696.812 us; speedup vs baseline: 1.8049x; 1.8049x over previous
//
#include <hip/hip_runtime.h>

#define B 4
#define CIN 256
#define T 8192
#define NL 24
#define SH 0.70710678118654752f
#define SKIP_SCALE 0.20412414523193150f  // (1/24)^0.5

typedef unsigned short u16;
typedef __attribute__((ext_vector_type(4))) float f32x4;
typedef __attribute__((ext_vector_type(8))) short s16x8;
typedef __attribute__((ext_vector_type(4))) short s16x4;

__device__ inline u16 f2bf(float f) {            // RNE float->bf16
  unsigned u = __float_as_uint(f);
  return (u16)((u + 0x7fffu + ((u >> 16) & 1u)) >> 16);
}
__device__ inline float gate_fn(float a, float g) {
  float e2 = __expf(-2.f * fabsf(a));
  float th = (1.f - e2) * __builtin_amdgcn_rcpf(1.f + e2);
  float sg = __builtin_amdgcn_rcpf(1.f + __expf(-g));
  return copysignf(th, a) * sg;
}

// ---------------- weight prep: one merged kernel ----------------
// wcv: [l][k][o(256)][c(128)] ; wso: [l][row(256: skip0-127,out128-255)][c]
__global__ void cvt_all(const float* __restrict__ conv_w, const float* __restrict__ skip_w,
                        const float* __restrict__ out_w, const float* __restrict__ first_w,
                        const float* __restrict__ last1_w, const float* __restrict__ last2_w,
                        u16* __restrict__ wcv, u16* __restrict__ wso, u16* __restrict__ wf,
                        u16* __restrict__ w1, u16* __restrict__ w2) {
  int i = blockIdx.x * 256 + threadIdx.x;
  if (i < 2359296) {  // conv: dst [l][k][o][c] <- src [l][o][c][k]
    int c = i & 127, o = (i >> 7) & 255, kk = (i >> 15) % 3, l = (i >> 15) / 3;
    wcv[i] = f2bf(conv_w[(((size_t)l * 256 + o) * 128 + c) * 3 + kk]);
    return;
  }
  i -= 2359296;
  if (i < 786432) {
    int c = i & 127, r = (i >> 7) & 255, l = i >> 15;
    float v = (r < 128) ? skip_w[((size_t)l * 128 + r) * 128 + c]
                        : out_w[((size_t)l * 128 + (r - 128)) * 128 + c];
    wso[i] = f2bf(v);
    return;
  }
  i -= 786432;
  if (i < 32768) { wf[i] = f2bf(first_w[i]); return; }
  i -= 32768;
  if (i < 16384) { w1[i] = f2bf(last1_w[i]); return; }
  i -= 16384;
  if (i < 32768) { w2[i] = f2bf(last2_w[i]); return; }
}
__global__ void sumsb_kernel(const float* __restrict__ sb, float* __restrict__ dst) {
  int c = threadIdx.x;  // 128
  float s = 0.f;
  for (int l = 0; l < NL; l++) s += sb[l * 128 + c];
  dst[c] = s;
}

// ---------------- first 1x1 conv: hf = first_w @ x + first_b (fp32 out) ----------------
__global__ __launch_bounds__(256, 2)
void first_kernel(const float* __restrict__ x, const u16* __restrict__ wf,
                  const float* __restrict__ fb, float* __restrict__ hf) {
  __shared__ u16 xT[64 * 256];  // 32KB, rows 512B, swizzled key (t&7)
  const int tid = threadIdx.x, wv = tid >> 6, lane = tid & 63, lo = lane & 15, hi = lane >> 4;
  const int t0 = blockIdx.x * 64, b = blockIdx.y;

  #pragma unroll
  for (int it = 0; it < 16; it++) {
    int idx = tid + it * 256;  // 4096 f32x4
    int c = idx >> 4, t4 = (idx & 15) << 2;
    f32x4 v = *(const f32x4*)(x + ((size_t)b * CIN + c) * T + t0 + t4);
    #pragma unroll
    for (int i = 0; i < 4; i++) {
      int t = t4 + i;
      *(u16*)((char*)xT + t * 512 + ((c * 2) ^ ((t & 7) << 4))) = f2bf(v[i]);
    }
  }
  __syncthreads();

  f32x4 acc[2][4];
  #pragma unroll
  for (int m = 0; m < 2; m++)
    #pragma unroll
    for (int n = 0; n < 4; n++) acc[m][n] = (f32x4){0.f, 0.f, 0.f, 0.f};
  #pragma unroll
  for (int s = 0; s < 8; s++) {
    s16x8 af[2], bf[4];
    #pragma unroll
    for (int m = 0; m < 2; m++)
      af[m] = *(const s16x8*)(wf + (size_t)(wv * 32 + m * 16 + lo) * CIN + s * 32 + hi * 8);
    #pragma unroll
    for (int n = 0; n < 4; n++) {
      int t = n * 16 + lo;
      bf[n] = *(const s16x8*)((const char*)xT + t * 512 + ((s * 64 + hi * 16) ^ ((t & 7) << 4)));
    }
    #pragma unroll
    for (int m = 0; m < 2; m++)
      #pragma unroll
      for (int n = 0; n < 4; n++)
        acc[m][n] = __builtin_amdgcn_mfma_f32_16x16x32_bf16(af[m], bf[n], acc[m][n], 0, 0, 0);
  }
  #pragma unroll
  for (int m = 0; m < 2; m++) {
    int c0 = wv * 32 + m * 16 + hi * 4;
    f32x4 bv = *(const f32x4*)(fb + c0);
    #pragma unroll
    for (int n = 0; n < 4; n++) {
      int t = n * 16 + lo;
      *(f32x4*)(hf + ((size_t)b * T + t0 + t) * 128 + c0) = acc[m][n] + bv;
    }
  }
}

// ---------------- fused layer-pair kernel ----------------
// Layers (2p, 2p+1), dilations (d1, d2). Block = (b, 64-t tile). No cross-block
// dependencies inside a launch: layer-1 is computed over 128 extended cols
// (ext cols' residual input read from global hf_in across tile boundary).
// Index conventions (all swizzle keys are t-aligned: key = (t - t0) & 7):
//   h0 LDS row j0 in [0,R0), R0=128+2*d1, global t = t0-64-2*d1+j0,
//       key = (j0+64-2*d1)&7
//   conv1 output col u in [0,128): t_out = t0-64+u; reads j0 = u + k*d1,
//       key = (lo+(k+6)*d1)&7  [u=n*16+lo]
//   zh row u: key = u&7 = lo&7
//   h1 LDS row u (overlaid into h_s rows [0,128)): key = u&7 = lo&7
//   conv2 (own 64 cols u2): reads h1 row j1 = u2 + 64-2*d2 + k*d2,
//       key = (lo+(k+6)*d2)&7
__global__ __launch_bounds__(512, 4)
void pair_kernel(const float* __restrict__ hf_in, float* __restrict__ hf_out,
                 float* __restrict__ skip,
                 const u16* __restrict__ wc1, const float* __restrict__ cb1,
                 const u16* __restrict__ ws1, const float* __restrict__ ob1,
                 const u16* __restrict__ wc2, const float* __restrict__ cb2,
                 const u16* __restrict__ ws2, const float* __restrict__ ob2,
                 int d1, int d2, int first) {
  extern __shared__ u16 lds[];
  u16* h_s = lds;              // 160 rows x 256B = 40KB (h0, then h1 overlay rows [0,128))
  u16* zh  = lds + 160 * 128;  // 128 rows x 256B = 32KB
  const int tid = threadIdx.x, wv = tid >> 6, lane = tid & 63, lo = lane & 15, hi = lane >> 4;
  const int tj = blockIdx.x, b = blockIdx.y, t0 = tj * 64;
  const int R0 = 128 + 2 * d1;

  // ---- stage h0: fp32 hf_in -> bf16 swizzled LDS ----
  for (int p = tid; p < R0 * 32; p += 512) {
    int j0 = p >> 5, cq = p & 31;
    int t = t0 - 64 - 2 * d1 + j0;
    f32x4 v = (f32x4){0.f, 0.f, 0.f, 0.f};
    if (t >= 0) v = *(const f32x4*)(hf_in + ((size_t)b * T + t) * 128 + cq * 4);
    s16x4 pk;
    #pragma unroll
    for (int j = 0; j < 4; j++) pk[j] = (short)f2bf(v[j]);
    *(s16x4*)((char*)h_s + j0 * 256 + ((cq * 8) ^ (((j0 + 64 - 2 * d1) & 7) << 4))) = pk;
  }
  __syncthreads();

  f32x4 A[2][8];
  const int oa = wv * 16, og = 128 + wv * 16;

  // ---- conv1 GEMM: N=128 cols ----
  #pragma unroll
  for (int m = 0; m < 2; m++)
    #pragma unroll
    for (int n = 0; n < 8; n++) A[m][n] = (f32x4){0.f, 0.f, 0.f, 0.f};
  #pragma unroll
  for (int k = 0; k < 3; k++) {
    const int st = ((lo + (k + 6) * d1) & 7) << 4;
    const int jb = k * d1;
    #pragma unroll
    for (int s = 0; s < 4; s++) {
      s16x8 af0 = *(const s16x8*)(wc1 + ((size_t)(k * 256 + oa + lo)) * 128 + s * 32 + hi * 8);
      s16x8 af1 = *(const s16x8*)(wc1 + ((size_t)(k * 256 + og + lo)) * 128 + s * 32 + hi * 8);
      const int cb_ = s * 64 + hi * 16;
      #pragma unroll
      for (int h2 = 0; h2 < 2; h2++) {
        s16x8 bf[4];
        #pragma unroll
        for (int nn = 0; nn < 4; nn++) {
          int j0 = (h2 * 4 + nn) * 16 + lo + jb;
          bf[nn] = *(const s16x8*)((const char*)h_s + j0 * 256 + (cb_ ^ st));
        }
        #pragma unroll
        for (int nn = 0; nn < 4; nn++) {
          A[0][h2 * 4 + nn] = __builtin_amdgcn_mfma_f32_16x16x32_bf16(af0, bf[nn], A[0][h2 * 4 + nn], 0, 0, 0);
          A[1][h2 * 4 + nn] = __builtin_amdgcn_mfma_f32_16x16x32_bf16(af1, bf[nn], A[1][h2 * 4 + nn], 0, 0, 0);
        }
      }
    }
  }
  // ---- gate1 -> zh (128 cols) ----
  {
    f32x4 ba = *(const f32x4*)(cb1 + oa + hi * 4);
    f32x4 bg = *(const f32x4*)(cb1 + og + hi * 4);
    #pragma unroll
    for (int n = 0; n < 8; n++) {
      int u = n * 16 + lo;
      s16x4 pk;
      #pragma unroll
      for (int j = 0; j < 4; j++)
        pk[j] = (short)f2bf(gate_fn(A[0][n][j] + ba[j], A[1][n][j] + bg[j]));
      *(s16x4*)((char*)zh + u * 256 + (((oa + hi * 4) * 2) ^ ((lo & 7) << 4))) = pk;
    }
  }
  __syncthreads();

  // ---- so1 GEMM: M=256 rows (skip waves 0-3 own cols only; out waves 4-7 all cols) ----
  const int ro = wv * 32;
  if (wv < 4) {
    #pragma unroll
    for (int m = 0; m < 2; m++)
      #pragma unroll
      for (int nn = 0; nn < 4; nn++) A[m][nn + 4] = (f32x4){0.f, 0.f, 0.f, 0.f};
    #pragma unroll
    for (int s = 0; s < 4; s++) {
      s16x8 af0 = *(const s16x8*)(ws1 + (size_t)(ro + lo) * 128 + s * 32 + hi * 8);
      s16x8 af1 = *(const s16x8*)(ws1 + (size_t)(ro + 16 + lo) * 128 + s * 32 + hi * 8);
      const int cb_ = s * 64 + hi * 16;
      s16x8 bf[4];
      #pragma unroll
      for (int nn = 0; nn < 4; nn++) {
        int u = (nn + 4) * 16 + lo;
        bf[nn] = *(const s16x8*)((const char*)zh + u * 256 + (cb_ ^ ((lo & 7) << 4)));
      }
      #pragma unroll
      for (int nn = 0; nn < 4; nn++) {
        A[0][nn + 4] = __builtin_amdgcn_mfma_f32_16x16x32_bf16(af0, bf[nn], A[0][nn + 4], 0, 0, 0);
        A[1][nn + 4] = __builtin_amdgcn_mfma_f32_16x16x32_bf16(af1, bf[nn], A[1][nn + 4], 0, 0, 0);
      }
    }
    // sacc parked in A[m][4..7] across conv2/gate2
  } else {
    #pragma unroll
    for (int m = 0; m < 2; m++)
      #pragma unroll
      for (int n = 0; n < 8; n++) A[m][n] = (f32x4){0.f, 0.f, 0.f, 0.f};
    #pragma unroll
    for (int s = 0; s < 4; s++) {
      s16x8 af0 = *(const s16x8*)(ws1 + (size_t)(ro + lo) * 128 + s * 32 + hi * 8);
      s16x8 af1 = *(const s16x8*)(ws1 + (size_t)(ro + 16 + lo) * 128 + s * 32 + hi * 8);
      const int cb_ = s * 64 + hi * 16;
      #pragma unroll
      for (int h2 = 0; h2 < 2; h2++) {
        s16x8 bf[4];
        #pragma unroll
        for (int nn = 0; nn < 4; nn++) {
          int u = (h2 * 4 + nn) * 16 + lo;
          bf[nn] = *(const s16x8*)((const char*)zh + u * 256 + (cb_ ^ ((lo & 7) << 4)));
        }
        #pragma unroll
        for (int nn = 0; nn < 4; nn++) {
          A[0][h2 * 4 + nn] = __builtin_amdgcn_mfma_f32_16x16x32_bf16(af0, bf[nn], A[0][h2 * 4 + nn], 0, 0, 0);
          A[1][h2 * 4 + nn] = __builtin_amdgcn_mfma_f32_16x16x32_bf16(af1, bf[nn], A[1][h2 * 4 + nn], 0, 0, 0);
        }
      }
    }
    // epilogue: h1 = (so1 + ob1 + h0)*sqrt(1/2); h1(t<0)=0; pack -> h_s rows [0,128)
    #pragma unroll
    for (int m = 0; m < 2; m++) {
      int c0 = (wv - 4) * 32 + m * 16 + hi * 4;
      f32x4 ob4 = *(const f32x4*)(ob1 + c0);
      #pragma unroll
      for (int n = 0; n < 8; n++) {
        int u = n * 16 + lo;
        int t_out = t0 - 64 + u;
        f32x4 h0 = (f32x4){0.f, 0.f, 0.f, 0.f};
        if (t_out >= 0) h0 = *(const f32x4*)(hf_in + ((size_t)b * T + t_out) * 128 + c0);
        f32x4 h1 = (A[m][n] + ob4 + h0) * SH;
        if (t_out < 0) h1 = (f32x4){0.f, 0.f, 0.f, 0.f};
        A[m][n] = h1;  // n in [4,8) kept as h1own for so2 residual
        s16x4 pk;
        #pragma unroll
        for (int j = 0; j < 4; j++) pk[j] = (short)f2bf(h1[j]);
        *(s16x4*)((char*)h_s + u * 256 + ((c0 * 2) ^ ((lo & 7) << 4))) = pk;
      }
    }
  }
  __syncthreads();

  // ---- conv2 GEMM: N=64 own cols, dilation d2, input h1 in h_s rows [0,128) ----
  #pragma unroll
  for (int m = 0; m < 2; m++)
    #pragma unroll
    for (int n = 0; n < 4; n++) A[m][n] = (f32x4){0.f, 0.f, 0.f, 0.f};
  #pragma unroll
  for (int k = 0; k < 3; k++) {
    const int st = ((lo + (k + 6) * d2) & 7) << 4;
    const int jb2 = 64 - 2 * d2 + k * d2;
    #pragma unroll
    for (int s = 0; s < 4; s++) {
      s16x8 af0 = *(const s16x8*)(wc2 + ((size_t)(k * 256 + oa + lo)) * 128 + s * 32 + hi * 8);
      s16x8 af1 = *(const s16x8*)(wc2 + ((size_t)(k * 256 + og + lo)) * 128 + s * 32 + hi * 8);
      const int cb_ = s * 64 + hi * 16;
      s16x8 bf[4];
      #pragma unroll
      for (int nn = 0; nn < 4; nn++) {
        int j1 = nn * 16 + lo + jb2;
        bf[nn] = *(const s16x8*)((const char*)h_s + j1 * 256 + (cb_ ^ st));
      }
      #pragma unroll
      for (int nn = 0; nn < 4; nn++) {
        A[0][nn] = __builtin_amdgcn_mfma_f32_16x16x32_bf16(af0, bf[nn], A[0][nn], 0, 0, 0);
        A[1][nn] = __builtin_amdgcn_mfma_f32_16x16x32_bf16(af1, bf[nn], A[1][nn], 0, 0, 0);
      }
    }
  }
  // ---- gate2 -> zh rows [0,64) ----
  {
    f32x4 ba = *(const f32x4*)(cb2 + oa + hi * 4);
    f32x4 bg = *(const f32x4*)(cb2 + og + hi * 4);
    #pragma unroll
    for (int n = 0; n < 4; n++) {
      int u = n * 16 + lo;
      s16x4 pk;
      #pragma unroll
      for (int j = 0; j < 4; j++)
        pk[j] = (short)f2bf(gate_fn(A[0][n][j] + ba[j], A[1][n][j] + bg[j]));
      *(s16x4*)((char*)zh + u * 256 + (((oa + hi * 4) * 2) ^ ((lo & 7) << 4))) = pk;
    }
  }
  __syncthreads();

  // ---- so2 GEMM: N=64 ----
  if (wv < 4) {  // skip rows: accumulate onto parked sacc (A[m][n+4]) then one RMW
    #pragma unroll
    for (int s = 0; s < 4; s++) {
      s16x8 af0 = *(const s16x8*)(ws2 + (size_t)(ro + lo) * 128 + s * 32 + hi * 8);
      s16x8 af1 = *(const s16x8*)(ws2 + (size_t)(ro + 16 + lo) * 128 + s * 32 + hi * 8);
      const int cb_ = s * 64 + hi * 16;
      s16x8 bf[4];
      #pragma unroll
      for (int nn = 0; nn < 4; nn++) {
        int u = nn * 16 + lo;
        bf[nn] = *(const s16x8*)((const char*)zh + u * 256 + (cb_ ^ ((lo & 7) << 4)));
      }
      #pragma unroll
      for (int nn = 0; nn < 4; nn++) {
        A[0][nn + 4] = __builtin_amdgcn_mfma_f32_16x16x32_bf16(af0, bf[nn], A[0][nn + 4], 0, 0, 0);
        A[1][nn + 4] = __builtin_amdgcn_mfma_f32_16x16x32_bf16(af1, bf[nn], A[1][nn + 4], 0, 0, 0);
      }
    }
    #pragma unroll
    for (int m = 0; m < 2; m++) {
      int c0 = ro + m * 16 + hi * 4;
      #pragma unroll
      for (int n = 0; n < 4; n++) {
        int t = t0 + n * 16 + lo;
        size_t off = ((size_t)b * T + t) * 128 + c0;
        f32x4 r = A[m][n + 4];
        if (!first) r += *(const f32x4*)(skip + off);
        *(f32x4*)(skip + off) = r;
      }
    }
  } else {  // out rows: h2 = (so2 + ob2 + h1own)*sqrt(1/2) -> hf_out
    #pragma unroll
    for (int m = 0; m < 2; m++)
      #pragma unroll
      for (int n = 0; n < 4; n++) A[m][n] = (f32x4){0.f, 0.f, 0.f, 0.f};
    #pragma unroll
    for (int s = 0; s < 4; s++) {
      s16x8 af0 = *(const s16x8*)(ws2 + (size_t)(ro + lo) * 128 + s * 32 + hi * 8);
      s16x8 af1 = *(const s16x8*)(ws2 + (size_t)(ro + 16 + lo) * 128 + s * 32 + hi * 8);
      const int cb_ = s * 64 + hi * 16;
      s16x8 bf[4];
      #pragma unroll
      for (int nn = 0; nn < 4; nn++) {
        int u = nn * 16 + lo;
        bf[nn] = *(const s16x8*)((const char*)zh + u * 256 + (cb_ ^ ((lo & 7) << 4)));
      }
      #pragma unroll
      for (int nn = 0; nn < 4; nn++) {
        A[0][nn] = __builtin_amdgcn_mfma_f32_16x16x32_bf16(af0, bf[nn], A[0][nn], 0, 0, 0);
        A[1][nn] = __builtin_amdgcn_mfma_f32_16x16x32_bf16(af1, bf[nn], A[1][nn], 0, 0, 0);
      }
    }
    #pragma unroll
    for (int m = 0; m < 2; m++) {
      int c0 = (wv - 4) * 32 + m * 16 + hi * 4;
      f32x4 ob4 = *(const f32x4*)(ob2 + c0);
      #pragma unroll
      for (int n = 0; n < 4; n++) {
        int t = t0 + n * 16 + lo;
        f32x4 h2v = (A[m][n] + ob4 + A[m][n + 4]) * SH;
        *(f32x4*)(hf_out + ((size_t)b * T + t) * 128 + c0) = h2v;
      }
    }
  }
}

// ---------------- fused head: relu((skip+sumsb)*scale) -> w1 relu -> w2 -> out ----------------
__global__ __launch_bounds__(256, 2)
void head_kernel(const float* __restrict__ skip, const float* __restrict__ sumsb,
                 const u16* __restrict__ w1, const float* __restrict__ b1v,
                 const u16* __restrict__ w2, const float* __restrict__ b2v,
                 float* __restrict__ out) {
  __shared__ u16 sT[64 * 128];   // 16KB
  __shared__ u16 s1T[64 * 128];  // 16KB
  const int tid = threadIdx.x, wv = tid >> 6, lane = tid & 63, lo = lane & 15, hi = lane >> 4;
  const int t0 = blockIdx.x * 64, b = blockIdx.y;

  #pragma unroll
  for (int it = 0; it < 8; it++) {
    int p = tid + it * 256;  // 2048 f32x4
    int t = p >> 5, cq = p & 31;
    f32x4 v = *(const f32x4*)(skip + ((size_t)b * T + t0 + t) * 128 + cq * 4);
    f32x4 sb4 = *(const f32x4*)(sumsb + cq * 4);
    s16x4 pk;
    #pragma unroll
    for (int j = 0; j < 4; j++) pk[j] = (short)f2bf(fmaxf((v[j] + sb4[j]) * SKIP_SCALE, 0.f));
    *(s16x4*)((char*)sT + t * 256 + ((cq * 8) ^ ((t & 7) << 4))) = pk;
  }
  __syncthreads();
  // GEMM1: s1 = relu(w1 @ sT + b1); 4 waves x 32 rows
  {
    f32x4 acc[2][4];
    #pragma unroll
    for (int m = 0; m < 2; m++)
      #pragma unroll
      for (int n = 0; n < 4; n++) acc[m][n] = (f32x4){0.f, 0.f, 0.f, 0.f};
    #pragma unroll
    for (int s = 0; s < 4; s++) {
      s16x8 af0 = *(const s16x8*)(w1 + (size_t)(wv * 32 + lo) * 128 + s * 32 + hi * 8);
      s16x8 af1 = *(const s16x8*)(w1 + (size_t)(wv * 32 + 16 + lo) * 128 + s * 32 + hi * 8);
      #pragma unroll
      for (int n = 0; n < 4; n++) {
        int t = n * 16 + lo;
        s16x8 bf = *(const s16x8*)((const char*)sT + t * 256 + ((s * 64 + hi * 16) ^ ((t & 7) << 4)));
        acc[0][n] = __builtin_amdgcn_mfma_f32_16x16x32_bf16(af0, bf, acc[0][n], 0, 0, 0);
        acc[1][n] = __builtin_amdgcn_mfma_f32_16x16x32_bf16(af1, bf, acc[1][n], 0, 0, 0);
      }
    }
    #pragma unroll
    for (int m = 0; m < 2; m++) {
      int c0 = wv * 32 + m * 16 + hi * 4;
      f32x4 bv = *(const f32x4*)(b1v + c0);
      #pragma unroll
      for (int n = 0; n < 4; n++) {
        int t = n * 16 + lo;
        s16x4 pk;
        #pragma unroll
        for (int j = 0; j < 4; j++) pk[j] = (short)f2bf(fmaxf(acc[m][n][j] + bv[j], 0.f));
        *(s16x4*)((char*)s1T + t * 256 + ((c0 * 2) ^ ((t & 7) << 4))) = pk;
      }
    }
  }
  __syncthreads();
  // GEMM2: out = w2 @ s1 + b2; 4 waves x 64 rows; out layout [B][256][T]
  {
    f32x4 acc[4][4];
    #pragma unroll
    for (int m = 0; m < 4; m++)
      #pragma unroll
      for (int n = 0; n < 4; n++) acc[m][n] = (f32x4){0.f, 0.f, 0.f, 0.f};
    #pragma unroll
    for (int s = 0; s < 4; s++) {
      s16x8 af[4];
      #pragma unroll
      for (int m = 0; m < 4; m++)
        af[m] = *(const s16x8*)(w2 + (size_t)(wv * 64 + m * 16 + lo) * 128 + s * 32 + hi * 8);
      #pragma unroll
      for (int n = 0; n < 4; n++) {
        int t = n * 16 + lo;
        s16x8 bf = *(const s16x8*)((const char*)s1T + t * 256 + ((s * 64 + hi * 16) ^ ((t & 7) << 4)));
        #pragma unroll
        for (int m = 0; m < 4; m++)
          acc[m][n] = __builtin_amdgcn_mfma_f32_16x16x32_bf16(af[m], bf, acc[m][n], 0, 0, 0);
      }
    }
    #pragma unroll
    for (int m = 0; m < 4; m++) {
      int c0 = wv * 64 + m * 16 + hi * 4;
      f32x4 bv = *(const f32x4*)(b2v + c0);
      #pragma unroll
      for (int n = 0; n < 4; n++) {
        int t = t0 + n * 16 + lo;
        f32x4 r = acc[m][n] + bv;
        #pragma unroll
        for (int j = 0; j < 4; j++) out[((size_t)b * CIN + c0 + j) * T + t] = r[j];
      }
    }
  }
}

// ---------------------------------------------------------------------------
extern "C" void kernel_launch(void* const* d_in, const int* in_sizes, int n_in,
                              void* d_out, int out_size, void* d_ws, size_t ws_size,
                              hipStream_t stream) {
  const float* x       = (const float*)d_in[0];
  const float* first_w = (const float*)d_in[1];
  const float* first_b = (const float*)d_in[2];
  const float* conv_w  = (const float*)d_in[3];
  const float* conv_b  = (const float*)d_in[4];
  const float* out_w   = (const float*)d_in[5];
  const float* out_b   = (const float*)d_in[6];
  const float* skip_w  = (const float*)d_in[7];
  const float* skip_b  = (const float*)d_in[8];
  const float* last1_w = (const float*)d_in[9];
  const float* last1_b = (const float*)d_in[10];
  const float* last2_w = (const float*)d_in[11];
  const float* last2_b = (const float*)d_in[12];
  float* out = (float*)d_out;

  // ws: weights (6.46 MB) + sumsb + skip fp32 (16 MB) = 23.2 MB (proven fits)
  u16* wcv = (u16*)d_ws;                         // 2,359,296
  u16* wso = wcv + (size_t)NL * 3 * 256 * 128;   // 786,432
  u16* wf  = wso + (size_t)NL * 256 * 128;       // 32,768
  u16* w1  = wf + 128 * 256;                     // 16,384
  u16* w2  = w1 + 128 * 128;                     // 32,768
  float* sumsb = (float*)(w2 + 256 * 128);       // 128 f32
  float* skipF = sumsb + 128;                    // 4,194,304 f32
  // hf double buffer lives in d_out (32 MB of 33.55 MB; dead before head writes out)
  float* hfA = (float*)d_out;
  float* hfB = hfA + (size_t)B * T * 128;

  cvt_all<<<12608, 256, 0, stream>>>(conv_w, skip_w, out_w, first_w, last1_w, last2_w,
                                     wcv, wso, wf, w1, w2);
  sumsb_kernel<<<1, 128, 0, stream>>>(skip_b, sumsb);

  dim3 grid(T / 64, B);
  first_kernel<<<grid, 256, 0, stream>>>(x, wf, first_b, hfA);

  for (int p = 0; p < NL / 2; p++) {
    int l1 = 2 * p, l2 = 2 * p + 1;
    int d1 = 1 << (l1 % 6), d2 = 1 << (l2 % 6);
    const float* hin = (p & 1) ? hfB : hfA;
    float* hout = (p & 1) ? hfA : hfB;
    pair_kernel<<<grid, 512, 73728, stream>>>(
        hin, hout, skipF,
        wcv + (size_t)l1 * 3 * 256 * 128, conv_b + (size_t)l1 * 256,
        wso + (size_t)l1 * 256 * 128, out_b + (size_t)l1 * 128,
        wcv + (size_t)l2 * 3 * 256 * 128, conv_b + (size_t)l2 * 256,
        wso + (size_t)l2 * 256 * 128, out_b + (size_t)l2 * 128,
        d1, d2, p == 0 ? 1 : 0);
  }
  head_kernel<<<grid, 256, 0, stream>>>(skipF, sumsb, w1, last1_b, w2, last2_b, out);
}